// Round 1
// baseline (222.939 us; speedup 1.0000x reference)
//
#include <hip/hip_runtime.h>
#include <hip/hip_bf16.h>

// Problem constants (match setup_inputs): B=2, N=512, D=128, H=256.
#define BB 2
#define NN 512
#define DD 128
#define HH 256

typedef __attribute__((ext_vector_type(4))) float  f32x4;
typedef __attribute__((ext_vector_type(8))) short  s16x8;  // 8 bf16 = 4 VGPRs (MFMA A/B frag)
typedef __attribute__((ext_vector_type(4))) int    i32x4;

// ---------------------------------------------------------------------------
// Stage 1: hA'[b,n,h] = b1[h] + sum_d PhiA[b,n,d]*W1[d][h]
//          hB [b,m,h] =          sum_d PhiB[b,m,d]*W1[D+d][h]
// 8 rows per block; thread = h (coalesced W1 reads, scalar Phi broadcasts).
// ---------------------------------------------------------------------------
#define NPB 8
__global__ __launch_bounds__(256) void stage1(
    const float* __restrict__ PhiA, const float* __restrict__ PhiB,
    const float* __restrict__ W1,  const float* __restrict__ b1,
    float* __restrict__ hA, float* __restrict__ hB) {
  const int h    = threadIdx.x;
  const int side = blockIdx.x & 1;           // 0 = A, 1 = B
  const int row0 = (blockIdx.x >> 1) * NPB;  // row among BB*NN
  const float* Phi = side ? PhiB : PhiA;
  const float* W   = W1 + side * DD * HH;
  float acc[NPB];
#pragma unroll
  for (int i = 0; i < NPB; i++) acc[i] = 0.f;
  for (int d = 0; d < DD; d++) {
    const float w = W[d * HH + h];
#pragma unroll
    for (int i = 0; i < NPB; i++)
      acc[i] = fmaf(Phi[(row0 + i) * DD + d], w, acc[i]);
  }
  const float bias = side ? 0.f : b1[h];
  float* out = side ? hB : hA;
#pragma unroll
  for (int i = 0; i < NPB; i++) out[(row0 + i) * HH + h] = acc[i] + bias;
}

// ---------------------------------------------------------------------------
// W2 [k][col] f32  ->  W2t [col][k] bf16   (so B-fragments are 16B contiguous)
// block = col, thread = k: writes coalesced, reads L2-served.
// ---------------------------------------------------------------------------
__global__ __launch_bounds__(256) void prep_w2(
    const float* __restrict__ W2, __hip_bfloat16* __restrict__ W2t) {
  const int col = blockIdx.x;
  const int k   = threadIdx.x;
  W2t[col * HH + k] = __float2bfloat16(W2[k * HH + col]);
}

// ---------------------------------------------------------------------------
// Main fused kernel.
//   Block = 256 threads (4 waves). Wave w owns cols [w*64, w*64+64).
//   W2 resident in registers: breg[ks][ct] lane l elem j =
//       W2[ks*32 + (l>>4)*8 + j][w*64 + ct*16 + (l&15)]
//   Per tile: 32 pairs = 2 n x 16 m. h1 = relu(hA'+hB) staged once in LDS
//   (bf16, XOR-swizzled), 64 MFMAs/wave, VALU epilogue relu(.+b2)*w3,
//   shfl reduce over 16 lanes, cross-wave LDS reduce.
// ---------------------------------------------------------------------------
#define TILES_TOTAL (BB * (NN / 2) * (NN / 16))  // 16384
#define GRID_MAIN 512

__global__ __launch_bounds__(256, 2) void pairmlp(
    const float* __restrict__ hA, const float* __restrict__ hB,
    const __hip_bfloat16* __restrict__ W2t, const float* __restrict__ b2,
    const float* __restrict__ W3, const float* __restrict__ b3,
    float* __restrict__ out) {
  __shared__ __align__(16) short h1[32 * 256];  // 16 KB, swizzled bf16
  __shared__ float red[4][32];

  const int tid  = threadIdx.x;
  const int lane = tid & 63;
  const int w    = tid >> 6;     // wave 0..3
  const int g    = lane >> 4;    // 0..3 (k-group / D-row group)
  const int lr   = lane & 15;    // A-row / B-col / D-col within tile

  // ---- persistent W2 fragments (128 VGPRs of bf16) ----
  s16x8 breg[8][4];
#pragma unroll
  for (int ks = 0; ks < 8; ks++)
#pragma unroll
    for (int ct = 0; ct < 4; ct++) {
      const int col = w * 64 + ct * 16 + lr;
      const int k0  = ks * 32 + g * 8;
      breg[ks][ct] = *reinterpret_cast<const s16x8*>(&W2t[col * HH + k0]);
    }

  float b2v[4], w3v[4];
#pragma unroll
  for (int ct = 0; ct < 4; ct++) {
    const int col = w * 64 + ct * 16 + lr;
    b2v[ct] = b2[col];
    w3v[ct] = W3[col];
  }
  const float b3v = b3[0];

  const int p = tid >> 3;  // 0..31: pair row for construction
  const int c = tid & 7;   // k-chunk of 32

  for (int t = blockIdx.x; t < TILES_TOTAL; t += GRID_MAIN) {
    const int mtile = t & 31;
    const int ntile = (t >> 5) & 255;
    const int bb    = t >> 13;
    const int n0    = ntile * 2;
    const int m0    = mtile * 16;

    // ---- construct h1 tile: 32 pairs x 256 k, bf16, swizzled ----
    const float* hAp = hA + ((bb * NN) + n0 + (p >> 4)) * HH + c * 32;
    const float* hBp = hB + ((bb * NN) + m0 + (p & 15)) * HH + c * 32;
#pragma unroll
    for (int q = 0; q < 4; q++) {
      f32x4 a0 = *reinterpret_cast<const f32x4*>(hAp + q * 8);
      f32x4 a1 = *reinterpret_cast<const f32x4*>(hAp + q * 8 + 4);
      f32x4 v0 = *reinterpret_cast<const f32x4*>(hBp + q * 8);
      f32x4 v1 = *reinterpret_cast<const f32x4*>(hBp + q * 8 + 4);
      float r0 = fmaxf(a0.x + v0.x, 0.f), r1 = fmaxf(a0.y + v0.y, 0.f);
      float r2 = fmaxf(a0.z + v0.z, 0.f), r3 = fmaxf(a0.w + v0.w, 0.f);
      float r4 = fmaxf(a1.x + v1.x, 0.f), r5 = fmaxf(a1.y + v1.y, 0.f);
      float r6 = fmaxf(a1.z + v1.z, 0.f), r7 = fmaxf(a1.w + v1.w, 0.f);
      union { __hip_bfloat162 h; int i; } u0, u1, u2, u3;
      u0.h = __float22bfloat162_rn(make_float2(r0, r1));
      u1.h = __float22bfloat162_rn(make_float2(r2, r3));
      u2.h = __float22bfloat162_rn(make_float2(r4, r5));
      u3.h = __float22bfloat162_rn(make_float2(r6, r7));
      i32x4 pv = {u0.i, u1.i, u2.i, u3.i};
      const int addr = (p * 512 + c * 64 + q * 16) ^ ((p & 7) << 4);
      *reinterpret_cast<i32x4*>(reinterpret_cast<char*>(h1) + addr) = pv;
    }
    __syncthreads();

    // ---- MFMA: 8 K-steps x (2 row-tiles x 4 col-tiles) ----
    f32x4 acc[2][4];
#pragma unroll
    for (int rt = 0; rt < 2; rt++)
#pragma unroll
      for (int ct = 0; ct < 4; ct++) acc[rt][ct] = (f32x4){0.f, 0.f, 0.f, 0.f};

#pragma unroll
    for (int ks = 0; ks < 8; ks++) {
      s16x8 afrag[2];
#pragma unroll
      for (int rt = 0; rt < 2; rt++) {
        const int row  = rt * 16 + lr;
        const int addr = (row * 512 + ks * 64 + g * 16) ^ ((row & 7) << 4);
        afrag[rt] = *reinterpret_cast<const s16x8*>(
            reinterpret_cast<const char*>(h1) + addr);
      }
#pragma unroll
      for (int rt = 0; rt < 2; rt++)
#pragma unroll
        for (int ct = 0; ct < 4; ct++)
          acc[rt][ct] = __builtin_amdgcn_mfma_f32_16x16x32_bf16(
              afrag[rt], breg[ks][ct], acc[rt][ct], 0, 0, 0);
    }

    // ---- epilogue: out[pair] = sum_col relu(h2+b2)*w3  (+b3 later) ----
    float part0[4] = {0.f, 0.f, 0.f, 0.f};
    float part1[4] = {0.f, 0.f, 0.f, 0.f};
#pragma unroll
    for (int ct = 0; ct < 4; ct++)
#pragma unroll
      for (int r = 0; r < 4; r++) {
        part0[r] += fmaxf(acc[0][ct][r] + b2v[ct], 0.f) * w3v[ct];
        part1[r] += fmaxf(acc[1][ct][r] + b2v[ct], 0.f) * w3v[ct];
      }
    // reduce across the 16 lanes (lr) holding different col groups
#pragma unroll
    for (int off = 1; off < 16; off <<= 1)
#pragma unroll
      for (int r = 0; r < 4; r++) {
        part0[r] += __shfl_xor(part0[r], off, 64);
        part1[r] += __shfl_xor(part1[r], off, 64);
      }
    if (lr == 0) {
#pragma unroll
      for (int r = 0; r < 4; r++) {
        red[w][g * 4 + r]      = part0[r];  // rt=0, m-offset g*4+r
        red[w][16 + g * 4 + r] = part1[r];  // rt=1
      }
    }
    __syncthreads();
    if (tid < 32) {
      const float v = red[0][tid] + red[1][tid] + red[2][tid] + red[3][tid] + b3v;
      const int n = n0 + (tid >> 4);
      const int m = m0 + (tid & 15);
      out[((bb * NN) + n) * NN + m] = v;
    }
    // next iter's h1 writes are ordered after this iter's reads by the
    // construction-phase __syncthreads() at the top of the next pass;
    // red reads above happen before that same barrier in program order.
  }
}

// ---------------------------------------------------------------------------
extern "C" void kernel_launch(void* const* d_in, const int* in_sizes, int n_in,
                              void* d_out, int out_size, void* d_ws, size_t ws_size,
                              hipStream_t stream) {
  const float* PhiA = (const float*)d_in[0];
  const float* PhiB = (const float*)d_in[1];
  const float* W1   = (const float*)d_in[2];
  const float* b1   = (const float*)d_in[3];
  const float* W2   = (const float*)d_in[4];
  const float* b2   = (const float*)d_in[5];
  const float* W3   = (const float*)d_in[6];
  const float* b3   = (const float*)d_in[7];
  float* out = (float*)d_out;

  char* ws = (char*)d_ws;
  float*          hA  = (float*)ws;                     // 1 MB
  float*          hB  = (float*)(ws + (1u << 20));      // 1 MB
  __hip_bfloat16* W2t = (__hip_bfloat16*)(ws + (2u << 20));  // 128 KB

  hipLaunchKernelGGL(stage1, dim3(2 * (BB * NN) / NPB), dim3(256), 0, stream,
                     PhiA, PhiB, W1, b1, hA, hB);
  hipLaunchKernelGGL(prep_w2, dim3(HH), dim3(256), 0, stream, W2, W2t);
  hipLaunchKernelGGL(pairmlp, dim3(GRID_MAIN), dim3(256), 0, stream,
                     hA, hB, W2t, b2, W3, b3, out);
}

// Round 2
// 166.437 us; speedup vs baseline: 1.3395x; 1.3395x over previous
//
#include <hip/hip_runtime.h>
#include <hip/hip_bf16.h>

// Problem constants (match setup_inputs): B=2, N=512, D=128, H=256.
#define BB 2
#define NN 512
#define DD 128
#define HH 256

typedef __attribute__((ext_vector_type(4))) float  f32x4;
typedef __attribute__((ext_vector_type(8))) short  s16x8;  // 8 bf16 (MFMA A/B frag)
typedef __attribute__((ext_vector_type(4))) int    i32x4;

__device__ __forceinline__ float bf16u(short u) {
  return __int_as_float(((int)(unsigned short)u) << 16);
}
// VALU-pipe 16-lane reduce step (DPP) — avoids DS-pipe ds_swizzle chains.
template <int CTRL>
__device__ __forceinline__ float dpp_add(float x) {
  int s = __builtin_amdgcn_update_dpp(0, __float_as_int(x), CTRL, 0xF, 0xF, true);
  return x + __int_as_float(s);
}

// ---------------------------------------------------------------------------
// Stage 1: hA[b,n,h] = bf16(b1[h] + sum_d PhiA*W1[:D]);  hB = bf16(PhiB*W1[D:])
// Phi rows staged in LDS (broadcast reads), W1 reads coalesced over h.
// ---------------------------------------------------------------------------
#define S1_ROWS 8
__global__ __launch_bounds__(256) void stage1(
    const float* __restrict__ PhiA, const float* __restrict__ PhiB,
    const float* __restrict__ W1,  const float* __restrict__ b1,
    __hip_bfloat16* __restrict__ hA, __hip_bfloat16* __restrict__ hB) {
  __shared__ float phis[S1_ROWS * DD];  // 4 KB
  const int side = blockIdx.x & 1;
  const int row0 = (blockIdx.x >> 1) * S1_ROWS;
  const float* Phi = side ? PhiB : PhiA;
  const float* W   = W1 + side * DD * HH;
  // 256 threads x f32x4 = 1024 floats = 8 rows x 128
  ((f32x4*)phis)[threadIdx.x] =
      ((const f32x4*)(Phi + (size_t)row0 * DD))[threadIdx.x];
  __syncthreads();
  const int h = threadIdx.x;
  float acc[S1_ROWS];
#pragma unroll
  for (int i = 0; i < S1_ROWS; i++) acc[i] = 0.f;
  for (int d0 = 0; d0 < DD; d0 += 4) {
    const float w0 = W[(d0 + 0) * HH + h];
    const float w1 = W[(d0 + 1) * HH + h];
    const float w2 = W[(d0 + 2) * HH + h];
    const float w3 = W[(d0 + 3) * HH + h];
#pragma unroll
    for (int i = 0; i < S1_ROWS; i++) {
      f32x4 ph = *(const f32x4*)&phis[i * DD + d0];
      acc[i] = fmaf(ph.x, w0, acc[i]);
      acc[i] = fmaf(ph.y, w1, acc[i]);
      acc[i] = fmaf(ph.z, w2, acc[i]);
      acc[i] = fmaf(ph.w, w3, acc[i]);
    }
  }
  const float bias = side ? 0.f : b1[h];
  __hip_bfloat16* o = (side ? hB : hA) + (size_t)row0 * HH + h;
#pragma unroll
  for (int i = 0; i < S1_ROWS; i++) o[i * HH] = __float2bfloat16(acc[i] + bias);
}

// ---------------------------------------------------------------------------
// W2 [k][col] f32  ->  W2t [col][k] bf16
// ---------------------------------------------------------------------------
__global__ __launch_bounds__(256) void prep_w2(
    const float* __restrict__ W2, __hip_bfloat16* __restrict__ W2t) {
  const int col = blockIdx.x;
  const int k   = threadIdx.x;
  W2t[col * HH + k] = __float2bfloat16(W2[k * HH + col]);
}

// ---------------------------------------------------------------------------
// Main fused kernel. Block = 4 waves; wave w owns cols [w*64, w*64+64).
// Per block: m0 fixed (hB rows invariant -> registers); 32 n-tiles looped.
// Per iter: ONE barrier; h1 double-buffered; DPP epilogue; atomicAdd store.
// ---------------------------------------------------------------------------
#define GRID_MAIN 512  // = BB*256 blocks; 32 iters each

__global__ __launch_bounds__(256, 2) void pairmlp(
    const __hip_bfloat16* __restrict__ hA, const __hip_bfloat16* __restrict__ hB,
    const __hip_bfloat16* __restrict__ W2t, const float* __restrict__ b2,
    const float* __restrict__ W3, const float* __restrict__ b3,
    float* __restrict__ out) {
  __shared__ __align__(16) short h1[2][32 * 256];  // 2 x 16 KB, swizzled bf16

  const int tid  = threadIdx.x;
  const int lane = tid & 63;
  const int w    = tid >> 6;   // wave 0..3
  const int g    = lane >> 4;  // 0..3
  const int lr   = lane & 15;
  const int bid  = blockIdx.x;
  const int bb    = bid >> 8;         // batch
  const int m0    = (bid & 31) * 16;  // fixed per block
  const int nbase = (bid & 255) >> 5; // 0..7

  // ---- persistent W2 fragments (128 VGPRs of bf16) ----
  s16x8 breg[8][4];
#pragma unroll
  for (int ks = 0; ks < 8; ks++)
#pragma unroll
    for (int ct = 0; ct < 4; ct++) {
      const int col = w * 64 + ct * 16 + lr;
      breg[ks][ct] = *reinterpret_cast<const s16x8*>(&W2t[col * HH + ks * 32 + g * 8]);
    }
  float b2v[4], w3v[4];
#pragma unroll
  for (int ct = 0; ct < 4; ct++) {
    const int col = w * 64 + ct * 16 + lr;
    b2v[ct] = b2[col];
    w3v[ct] = W3[col];
  }
  const float b3q = b3[0] * 0.25f;  // 4 waves each add b3/4

  const int p = tid >> 3;  // 0..31: pair row for construction
  const int c = tid & 7;   // k-chunk of 32

  // ---- loop-invariant hB row chunk in registers (bf16, 16 VGPRs) ----
  s16x8 hbr[4];
  {
    const __hip_bfloat16* hBp =
        hB + ((size_t)(bb * NN + m0 + (p & 15))) * HH + c * 32;
#pragma unroll
    for (int q = 0; q < 4; q++)
      hbr[q] = *reinterpret_cast<const s16x8*>(hBp + q * 8);
  }
  const __hip_bfloat16* hAbase =
      hA + ((size_t)(bb * NN + (p >> 4))) * HH + c * 32;

  auto loadA = [&](int n0, s16x8* av) {
    const __hip_bfloat16* hAp = hAbase + (size_t)n0 * HH;
#pragma unroll
    for (int q = 0; q < 4; q++)
      av[q] = *reinterpret_cast<const s16x8*>(hAp + q * 8);
  };
  auto build = [&](const s16x8* av, int buf) {
#pragma unroll
    for (int q = 0; q < 4; q++) {
      int pk[4];
#pragma unroll
      for (int jj = 0; jj < 4; jj++) {
        float r0 = fmaxf(bf16u(av[q][2 * jj])     + bf16u(hbr[q][2 * jj]),     0.f);
        float r1 = fmaxf(bf16u(av[q][2 * jj + 1]) + bf16u(hbr[q][2 * jj + 1]), 0.f);
        union { __hip_bfloat162 hh; int ii; } u;
        u.hh = __float22bfloat162_rn(make_float2(r0, r1));
        pk[jj] = u.ii;
      }
      i32x4 pv = {pk[0], pk[1], pk[2], pk[3]};
      const int addr = (p * 512 + c * 64 + q * 16) ^ ((p & 7) << 4);
      *reinterpret_cast<i32x4*>(reinterpret_cast<char*>(h1[buf]) + addr) = pv;
    }
  };

  // prologue: construct tile k=0 into buffer 0
  {
    s16x8 av[4];
    loadA(2 * nbase, av);
    build(av, 0);
  }

  for (int k = 0; k < 32; k++) {
    const int cur = k & 1;
    const int n0  = 2 * nbase + 16 * k;
    __syncthreads();  // h1[cur] ready for all waves; prev reads of h1[cur^1] drained

    // issue next tile's hA loads early (latency hidden under MFMA phase)
    s16x8 av[4];
    if (k < 31) loadA(n0 + 16, av);

    // ---- MFMA: 8 K-steps x (2 row-tiles x 4 col-tiles) ----
    f32x4 acc[2][4];
#pragma unroll
    for (int rt = 0; rt < 2; rt++)
#pragma unroll
      for (int ct = 0; ct < 4; ct++) acc[rt][ct] = (f32x4){0.f, 0.f, 0.f, 0.f};
#pragma unroll
    for (int ks = 0; ks < 8; ks++) {
      s16x8 afrag[2];
#pragma unroll
      for (int rt = 0; rt < 2; rt++) {
        const int row  = rt * 16 + lr;
        const int addr = (row * 512 + ks * 64 + g * 16) ^ ((row & 7) << 4);
        afrag[rt] = *reinterpret_cast<const s16x8*>(
            reinterpret_cast<const char*>(h1[cur]) + addr);
      }
#pragma unroll
      for (int rt = 0; rt < 2; rt++)
#pragma unroll
        for (int ct = 0; ct < 4; ct++)
          acc[rt][ct] = __builtin_amdgcn_mfma_f32_16x16x32_bf16(
              afrag[rt], breg[ks][ct], acc[rt][ct], 0, 0, 0);
    }

    // construct next tile into the other buffer (no barrier needed: WAR
    // against iter k-1 readers resolved by this iter's top barrier)
    if (k < 31) build(av, cur ^ 1);

    // ---- epilogue: DPP 16-lane reduce on the VALU pipe, then atomics ----
    float part[2][4];
#pragma unroll
    for (int rt = 0; rt < 2; rt++)
#pragma unroll
      for (int r = 0; r < 4; r++) {
        float s = 0.f;
#pragma unroll
        for (int ct = 0; ct < 4; ct++)
          s += fmaxf(acc[rt][ct][r] + b2v[ct], 0.f) * w3v[ct];
        s = dpp_add<0xB1>(s);    // + lane^1 (quad_perm [1,0,3,2])
        s = dpp_add<0x4E>(s);    // + lane^2 (quad_perm [2,3,0,1])
        s = dpp_add<0x141>(s);   // + other quad (row_half_mirror)
        s = dpp_add<0x140>(s);   // + other half (row_mirror)
        part[rt][r] = s;
      }
    if (lr == 0) {
#pragma unroll
      for (int rt = 0; rt < 2; rt++)
#pragma unroll
        for (int r = 0; r < 4; r++)
          atomicAdd(&out[((size_t)(bb * NN + n0 + rt)) * NN + m0 + g * 4 + r],
                    part[rt][r] + b3q);
    }
  }
}

// ---------------------------------------------------------------------------
extern "C" void kernel_launch(void* const* d_in, const int* in_sizes, int n_in,
                              void* d_out, int out_size, void* d_ws, size_t ws_size,
                              hipStream_t stream) {
  const float* PhiA = (const float*)d_in[0];
  const float* PhiB = (const float*)d_in[1];
  const float* W1   = (const float*)d_in[2];
  const float* b1   = (const float*)d_in[3];
  const float* W2   = (const float*)d_in[4];
  const float* b2   = (const float*)d_in[5];
  const float* W3   = (const float*)d_in[6];
  const float* b3   = (const float*)d_in[7];
  float* out = (float*)d_out;

  char* ws = (char*)d_ws;
  __hip_bfloat16* hA  = (__hip_bfloat16*)ws;                    // 512 KB
  __hip_bfloat16* hB  = (__hip_bfloat16*)(ws + (512u << 10));   // 512 KB
  __hip_bfloat16* W2t = (__hip_bfloat16*)(ws + (1024u << 10));  // 128 KB

  hipMemsetAsync(d_out, 0, (size_t)out_size * sizeof(float), stream);
  hipLaunchKernelGGL(stage1, dim3(2 * (BB * NN) / S1_ROWS), dim3(256), 0, stream,
                     PhiA, PhiB, W1, b1, hA, hB);
  hipLaunchKernelGGL(prep_w2, dim3(HH), dim3(256), 0, stream, W2, W2t);
  hipLaunchKernelGGL(pairmlp, dim3(GRID_MAIN), dim3(256), 0, stream,
                     hA, hB, W2t, b2, W3, b3, out);
}